// Round 1
// baseline (1043.542 us; speedup 1.0000x reference)
//
#include <hip/hip_runtime.h>
#include <float.h>
#include <math.h>

// Problem constants (from reference setup_inputs)
#define LQ   512
#define LL   4096      // key length
#define DD   64        // d_qk == d_v
#define KEEP 32        // MAX_SET_SIZE
#define QT   2         // query rows per block
#define NT   256       // threads per block
#define NTILES (LL / NT)   // 16

__global__ __launch_bounds__(NT, 4) void ga_fused(
    const float* __restrict__ q,
    const float* __restrict__ kmat,
    const float* __restrict__ vmat,
    const int*   __restrict__ mask,
    float*       __restrict__ out)
{
    __shared__ float sc[QT][LL];                       // masked scores, 32 KB
    __shared__ float q_s[QT][DD];
    __shared__ unsigned long long mbits[QT][LL / 64];  // mask bitmap
    __shared__ float redv[4][QT][DD];                  // mean-pool cross-wave reduce
    __shared__ float mean_s[QT][DD];
    __shared__ int   count_s[QT];
    __shared__ int   sel_idx[QT][KEEP];
    __shared__ float sel_val[QT][KEEP];
    __shared__ int   sel_cnt[QT];
    __shared__ float wred[4];
    __shared__ int   ired[4];
    __shared__ int   brk;
    __shared__ float wgt[QT][KEEP];

    const int t    = threadIdx.x;
    const int wave = t >> 6;
    const int lane = t & 63;
    const int n0   = blockIdx.x * QT;   // first query row of this block
    const int b    = n0 / LQ;           // batch (QT divides LQ, no crossing)

    if (t < QT) sel_cnt[t] = 0;
    if (t < QT * DD) {
        int qt = t >> 6;                // DD == 64
        int d  = t & 63;
        q_s[qt][d] = q[(size_t)(n0 + qt) * DD + d];
    }
    __syncthreads();

    // ---- Phase A: scores (masked) + mask bitmap -----------------------------
    const float4* q4_0 = reinterpret_cast<const float4*>(&q_s[0][0]);
    const float4* q4_1 = reinterpret_cast<const float4*>(&q_s[1][0]);
    for (int tile = 0; tile < NTILES; ++tile) {
        int l = tile * NT + t;
        const float4* kr = reinterpret_cast<const float4*>(kmat + (size_t)(b * LL + l) * DD);
        float d0 = 0.f, d1 = 0.f;
        #pragma unroll
        for (int i = 0; i < 16; ++i) {
            float4 kk = kr[i];
            float4 qa = q4_0[i];
            float4 qb = q4_1[i];
            d0 += kk.x * qa.x + kk.y * qa.y + kk.z * qa.z + kk.w * qa.w;
            d1 += kk.x * qb.x + kk.y * qb.y + kk.z * qb.z + kk.w * qb.w;
        }
        int mv0 = mask[(size_t)n0 * LL + l];
        int mv1 = mask[(size_t)(n0 + 1) * LL + l];
        unsigned long long b0 = __ballot(mv0 != 0);
        unsigned long long b1 = __ballot(mv1 != 0);
        int widx = tile * 4 + wave;     // l >> 6 for this wave's span
        if (lane == 0) { mbits[0][widx] = b0; mbits[1][widx] = b1; }
        sc[0][l] = mv0 ? d0 * 0.125f : -FLT_MAX;
        sc[1][l] = mv1 ? d1 * 0.125f : -FLT_MAX;
    }
    __syncthreads();

    // ---- mask popcounts (wave w handles row w) ------------------------------
    if (wave < QT) {
        int c = (int)__popcll(mbits[wave][lane]);
        for (int off = 32; off >= 1; off >>= 1) c += __shfl_down(c, off);
        if (lane == 0) count_s[wave] = c;
    }

    // ---- Phase B: masked mean of v ------------------------------------------
    // thread = (g = wave, d = lane); wave g covers rows l == g (mod 4)
    {
        float acc0 = 0.f, acc1 = 0.f;
        const int g = wave, d = lane;
        for (int wi = 0; wi < LL / 64; ++wi) {
            unsigned long long w0 = mbits[0][wi];
            unsigned long long w1 = mbits[1][wi];
            const float* vp = vmat + (size_t)(b * LL + wi * 64 + g) * DD + d;
            #pragma unroll 4
            for (int ii = 0; ii < 16; ++ii) {
                int sh = g + 4 * ii;
                float vv = vp[(size_t)(4 * ii) * DD];
                if ((w0 >> sh) & 1ULL) acc0 += vv;
                if ((w1 >> sh) & 1ULL) acc1 += vv;
            }
        }
        redv[g][0][d] = acc0;
        redv[g][1][d] = acc1;
    }
    __syncthreads();
    if (t < QT * DD) {
        int qt = t >> 6, dd = t & 63;
        float s = redv[0][qt][dd] + redv[1][qt][dd] + redv[2][qt][dd] + redv[3][qt][dd];
        int c = count_s[qt]; if (c < 1) c = 1;
        mean_s[qt][dd] = s / (float)c;
    }
    __syncthreads();

    // ---- Phase C: iterative top-32 (tie-break: lower index, matches top_k) --
    for (int qt = 0; qt < QT; ++qt) {
        for (int s = 0; s < KEEP; ++s) {
            float m = -FLT_MAX; int mi = LL;
            for (int j = 0; j < NTILES; ++j) {
                int l = j * NT + t;
                float val = sc[qt][l];
                if (val > m) { m = val; mi = l; }   // ascending l: keeps lowest idx on tie
            }
            for (int off = 32; off >= 1; off >>= 1) {
                float ov = __shfl_down(m, off);
                int   oi = __shfl_down(mi, off);
                if (ov > m || (ov == m && oi < mi)) { m = ov; mi = oi; }
            }
            if (lane == 0) { wred[wave] = m; ired[wave] = mi; }
            __syncthreads();
            if (t == 0) {
                float bv = wred[0]; int bi = ired[0];
                for (int w2 = 1; w2 < 4; ++w2) {
                    float ov = wred[w2]; int oi = ired[w2];
                    if (ov > bv || (ov == bv && oi < bi)) { bv = ov; bi = oi; }
                }
                if (bv > -FLT_MAX) {                 // a real (masked) score
                    sel_idx[qt][s] = bi;
                    sel_val[qt][s] = bv;
                    sel_cnt[qt]    = s + 1;
                    sc[qt][bi] = -FLT_MAX;           // remove from next rounds
                    brk = 0;
                } else {
                    brk = 1;                          // ran out of masked entries
                }
            }
            __syncthreads();
            if (brk) break;
        }
    }

    // ---- Phase D: softmax over selected + weighted v gather -----------------
    if (wave < QT) {
        int qt = wave;
        int S = sel_cnt[qt];
        if (S > 0) {
            float mx = sel_val[qt][0];               // first selected == max
            float e = 0.f;
            if (lane < S) e = expf(sel_val[qt][lane] - mx);
            float ssum = e;
            for (int off = 32; off >= 1; off >>= 1) ssum += __shfl_xor(ssum, off);
            if (lane < S) wgt[qt][lane] = e / ssum;
        }
    }
    __syncthreads();
    if (wave < QT) {
        int qt = wave;
        int S = sel_cnt[qt];
        float o = mean_s[qt][lane];                  // lane == output dim d
        for (int j = 0; j < S; ++j) {
            o += wgt[qt][j] * vmat[(size_t)(b * LL + sel_idx[qt][j]) * DD + lane];
        }
        out[(size_t)(n0 + qt) * DD + lane] = o;
    }
}

extern "C" void kernel_launch(void* const* d_in, const int* in_sizes, int n_in,
                              void* d_out, int out_size, void* d_ws, size_t ws_size,
                              hipStream_t stream) {
    const float* q    = (const float*)d_in[0];
    const float* kmat = (const float*)d_in[1];
    const float* vmat = (const float*)d_in[2];
    const int*   mask = (const int*)d_in[3];
    float* out = (float*)d_out;

    const int n_rows = 8 * LQ;                 // B * Lq = 4096
    dim3 grid(n_rows / QT), block(NT);
    hipLaunchKernelGGL(ga_fused, grid, block, 0, stream, q, kmat, vmat, mask, out);
}